// Round 2
// baseline (82.398 us; speedup 1.0000x reference)
//
#include <hip/hip_runtime.h>
#include <math.h>

// Problem constants (fixed by the reference)
#define G      32
#define NA     1024
#define C      4
#define NMAX   6
#define KHALF  1098      // half of the 2196 nonzero k-vectors (inversion symmetry)
#define KSLICES 18       // ceil(1098/64)
#define WAVES  8
#define BLOCK  (WAVES * 64)
#define ATOMS_PER_WAVE (NA / WAVES)   // 128

__global__ __launch_bounds__(BLOCK)
void ewald_recip_kernel(const float* __restrict__ q,
                        const float* __restrict__ pos,
                        const float* __restrict__ cell,
                        float* __restrict__ out)
{
    // pos.xyz + pad, q0..3 per atom -> 32 KiB; broadcast-read by all waves
    __shared__ __align__(16) float s_atom[NA][8];
    // per-wave partial S (4 re + 4 im) per k-lane -> 16 KiB
    __shared__ float s_red[WAVES][64][8];

    const int b    = blockIdx.x;
    const int g    = b / KSLICES;
    const int ks   = b % KSLICES;
    const int t    = threadIdx.x;
    const int wave = t >> 6;
    const int lane = t & 63;

    // ---- stage atoms of this graph into LDS (coalesced-ish) ----
    const float* posg = pos + (size_t)g * NA * 3;
    const float* qg   = q   + (size_t)g * NA * 4;
    for (int a = t; a < NA; a += BLOCK) {
        float px = posg[a * 3 + 0];
        float py = posg[a * 3 + 1];
        float pz = posg[a * 3 + 2];
        const float4 qa = *reinterpret_cast<const float4*>(qg + (size_t)a * 4);
        s_atom[a][0] = px; s_atom[a][1] = py; s_atom[a][2] = pz; s_atom[a][3] = 0.f;
        s_atom[a][4] = qa.x; s_atom[a][5] = qa.y; s_atom[a][6] = qa.z; s_atom[a][7] = qa.w;
    }

    // ---- per-thread (wave-uniform) cell inverse + det ----
    const float* M = cell + (size_t)g * 9;
    const float m00 = M[0], m01 = M[1], m02 = M[2];
    const float m10 = M[3], m11 = M[4], m12 = M[5];
    const float m20 = M[6], m21 = M[7], m22 = M[8];
    // cofactors c_ij = cofactor(i,j);  inv[d][j] = c_{j d} / det
    const float c00 =  (m11 * m22 - m12 * m21);
    const float c01 = -(m10 * m22 - m12 * m20);
    const float c02 =  (m10 * m21 - m11 * m20);
    const float c10 = -(m01 * m22 - m02 * m21);
    const float c11 =  (m00 * m22 - m02 * m20);
    const float c12 = -(m00 * m21 - m01 * m20);
    const float c20 =  (m01 * m12 - m02 * m11);
    const float c21 = -(m00 * m12 - m02 * m10);
    const float c22 =  (m00 * m11 - m01 * m10);
    const float det    = m00 * c00 + m01 * c01 + m02 * c02;
    const float invdet = 1.0f / det;

    // ---- decode this lane's half-space k integer triple ----
    const int  kk    = ks * 64 + lane;
    const bool valid = (kk < KHALF);
    int n1, n2, n3;
    if (kk < 1014) {               // n1 in [1,6], n2,n3 full range
        n1 = 1 + kk / 169;
        const int r = kk - (n1 - 1) * 169;
        n2 = r / 13 - 6;
        n3 = r - (r / 13) * 13 - 6;
    } else if (kk < 1092) {        // n1 = 0, n2 in [1,6]
        const int j = kk - 1014;
        n1 = 0;
        n2 = 1 + j / 13;
        n3 = j - (j / 13) * 13 - 6;
    } else {                        // n1 = n2 = 0, n3 in [1,6]
        n1 = 0; n2 = 0;
        n3 = kk - 1091;            // garbage for kk>=1098, masked later
    }
    const float fn1 = (float)n1, fn2 = (float)n2, fn3 = (float)n3;

    // k-vector in REVOLUTION units (no 2*pi): kr[d] = sum_j n_j * inv[d][j]
    const float kr0 = (fn1 * c00 + fn2 * c10 + fn3 * c20) * invdet;
    const float kr1 = (fn1 * c01 + fn2 * c11 + fn3 * c21) * invdet;
    const float kr2 = (fn1 * c02 + fn2 * c12 + fn3 * c22) * invdet;

    __syncthreads();

    // ---- inner loop: this wave's atom chunk, broadcast LDS reads ----
    float sr0 = 0.f, sr1 = 0.f, sr2 = 0.f, sr3 = 0.f;
    float si0 = 0.f, si1 = 0.f, si2 = 0.f, si3 = 0.f;
    const int a0 = wave * ATOMS_PER_WAVE;
    #pragma unroll 4
    for (int a = 0; a < ATOMS_PER_WAVE; ++a) {
        const float* at = s_atom[a0 + a];
        const float4 pp = *reinterpret_cast<const float4*>(at);
        const float4 qa = *reinterpret_cast<const float4*>(at + 4);
        // phase in revolutions
        const float ph = pp.x * kr0 + pp.y * kr1 + pp.z * kr2;
        const float u  = __builtin_amdgcn_fractf(ph);   // [0,1)
        const float sn = __builtin_amdgcn_sinf(u);      // sin(2*pi*u)
        const float cs = __builtin_amdgcn_cosf(u);      // cos(2*pi*u)
        sr0 = fmaf(qa.x, cs, sr0);  si0 = fmaf(qa.x, sn, si0);
        sr1 = fmaf(qa.y, cs, sr1);  si1 = fmaf(qa.y, sn, si1);
        sr2 = fmaf(qa.z, cs, sr2);  si2 = fmaf(qa.z, sn, si2);
        sr3 = fmaf(qa.w, cs, sr3);  si3 = fmaf(qa.w, sn, si3);
    }

    // ---- reduce partial S across waves via LDS ----
    {
        float* rp = s_red[wave][lane];
        rp[0] = sr0; rp[1] = sr1; rp[2] = sr2; rp[3] = sr3;
        rp[4] = si0; rp[5] = si1; rp[6] = si2; rp[7] = si3;
    }
    __syncthreads();

    if (t < 64) {
        float r0 = 0.f, r1 = 0.f, r2 = 0.f, r3 = 0.f;
        float i0 = 0.f, i1 = 0.f, i2 = 0.f, i3 = 0.f;
        #pragma unroll
        for (int w = 0; w < WAVES; ++w) {
            const float* p = s_red[w][lane];
            r0 += p[0]; r1 += p[1]; r2 += p[2]; r3 += p[3];
            i0 += p[4]; i1 += p[5]; i2 += p[6]; i3 += p[7];
        }
        const float s2 = r0 * r0 + r1 * r1 + r2 * r2 + r3 * r3
                       + i0 * i0 + i1 * i1 + i2 * i2 + i3 * i3;
        const float kk2 = kr0 * kr0 + kr1 * kr1 + kr2 * kr2;
        const float fourpi2 = 4.0f * (float)M_PI * (float)M_PI;
        const float k2 = fourpi2 * kk2;                      // true |k|^2
        const float wt = 4.0f * (float)M_PI * __expf(-0.5f * k2) / fmaxf(k2, 1e-12f);
        // half-space sum: E = (1/(2V)) * 2 * sum_half = sum_half / V
        float contrib = valid ? wt * s2 : 0.0f;
        #pragma unroll
        for (int off = 32; off > 0; off >>= 1)
            contrib += __shfl_down(contrib, off, 64);
        if (lane == 0)
            atomicAdd(&out[g], contrib * fabsf(invdet));
    }
}

extern "C" void kernel_launch(void* const* d_in, const int* in_sizes, int n_in,
                              void* d_out, int out_size, void* d_ws, size_t ws_size,
                              hipStream_t stream) {
    const float* q    = (const float*)d_in[0];   // [G*NA, C]
    const float* pos  = (const float*)d_in[1];   // [G*NA, 3]
    const float* cell = (const float*)d_in[2];   // [G, 3, 3]
    // d_in[3] = batch (unused: equal-sized sorted segments)
    float* out = (float*)d_out;                  // [G] f32

    hipMemsetAsync(out, 0, G * sizeof(float), stream);

    dim3 grid(G * KSLICES);
    dim3 block(BLOCK);
    ewald_recip_kernel<<<grid, block, 0, stream>>>(q, pos, cell, out);
}